// Round 5
// baseline (232.803 us; speedup 1.0000x reference)
//
#include <hip/hip_runtime.h>
#include <stdint.h>

#define D_MODEL 512
#define INNER   1024
#define NCAT    4096
#define BATCH   8
#define SEQ     2048
#define ROWS    (BATCH*SEQ)
#define LN_EPS  1e-5f
#define CHUNK   64
#define NCHUNK  (SEQ/CHUNK)

typedef unsigned short u16;
typedef unsigned int   u32;
typedef __attribute__((ext_vector_type(8))) short bf16x8;
typedef __attribute__((ext_vector_type(4))) float f32x4;

__device__ __forceinline__ u16 f2bf(float f) {
  u32 u = __builtin_bit_cast(u32, f);
  return (u16)((u + 0x7FFFu + ((u >> 16) & 1u)) >> 16);
}
__device__ __forceinline__ float bf2f(u32 lo) {
  return __builtin_bit_cast(float, lo << 16);
}
__device__ __forceinline__ float sigf(float x){ return 1.f/(1.f+__expf(-x)); }

__device__ __forceinline__ void glds16(const void* g, void* l) {
  __builtin_amdgcn_global_load_lds((const __attribute__((address_space(1))) void*)g,
                                   (__attribute__((address_space(3))) void*)l, 16, 0, 0);
}

#define MFMA16(a,b,c) __builtin_amdgcn_mfma_f32_16x16x32_bf16((a),(b),(c),0,0,0)

// ---------------- LayerNorm: one wave per row of 512, write bf16 ----------------
__global__ __launch_bounds__(256) void ln_kernel(const float* __restrict__ x,
    const float* __restrict__ lw, const float* __restrict__ lb,
    u16* __restrict__ xn) {
  const int row  = blockIdx.x * 4 + (threadIdx.x >> 6);
  const int lane = threadIdx.x & 63;
  const float4* xr = (const float4*)(x + (size_t)row * D_MODEL);
  float4 v0 = xr[lane*2], v1 = xr[lane*2+1];
  float s  = v0.x+v0.y+v0.z+v0.w + v1.x+v1.y+v1.z+v1.w;
  float s2 = v0.x*v0.x+v0.y*v0.y+v0.z*v0.z+v0.w*v0.w
           + v1.x*v1.x+v1.y*v1.y+v1.z*v1.z+v1.w*v1.w;
  #pragma unroll
  for (int o=32;o;o>>=1){ s += __shfl_xor(s,o); s2 += __shfl_xor(s2,o); }
  const float mu = s * (1.f/D_MODEL);
  const float rs = rsqrtf(s2*(1.f/D_MODEL) - mu*mu + LN_EPS);
  const float4* wv = (const float4*)lw; const float4* bv = (const float4*)lb;
  float4 w0 = wv[lane*2], w1 = wv[lane*2+1];
  float4 b0 = bv[lane*2], b1 = bv[lane*2+1];
  u32 p0 = (u32)f2bf((v0.x-mu)*rs*w0.x+b0.x) | ((u32)f2bf((v0.y-mu)*rs*w0.y+b0.y)<<16);
  u32 p1 = (u32)f2bf((v0.z-mu)*rs*w0.z+b0.z) | ((u32)f2bf((v0.w-mu)*rs*w0.w+b0.w)<<16);
  u32 p2 = (u32)f2bf((v1.x-mu)*rs*w1.x+b1.x) | ((u32)f2bf((v1.y-mu)*rs*w1.y+b1.y)<<16);
  u32 p3 = (u32)f2bf((v1.z-mu)*rs*w1.z+b1.z) | ((u32)f2bf((v1.w-mu)*rs*w1.w+b1.w)<<16);
  ((uint4*)(xn + (size_t)row * D_MODEL))[lane] = make_uint4(p0,p1,p2,p3);
}

// ---------------- fp32 -> bf16 convert (weights) ----------------
__global__ void cvt_kernel(const float* __restrict__ s, u16* __restrict__ d, int n) {
  for (int i = blockIdx.x*blockDim.x+threadIdx.x; i < n; i += gridDim.x*blockDim.x)
    d[i] = f2bf(s[i]);
}

// ---------------- block swizzle: XCD-chunked + L2-sized (GMxGN) groups ----------------
__device__ __forceinline__ void sched_blk(int nbm, int nbn, int GM, int GN,
                                          int& bM, int& bN) {
  const int nwg = nbm * nbn;
  const int bid = blockIdx.x;
  const int cpx = nwg >> 3;
  const int swz = (bid & 7) * cpx + (bid >> 3);   // contiguous chunk per XCD
  const int gsz = GM * GN;
  const int g   = swz / gsz, loc = swz - g * gsz;
  const int ngn = nbn / GN;
  const int gm  = g / ngn,  gn  = g - gm * ngn;
  bM = gm * GM + (loc % GM);
  bN = gn * GN + (loc / GM);
}

// ================= GEMM1: 256x256 tile, BK=64, 8 waves, 4-phase K-tiles =================
// Counted-vmcnt pipeline (stage distance 2):
//   tile kt's phases read slot S=kt&1; after P2's wait, S is fully consumed,
//   so tile kt+2 stages into S during P2 (A) and P3 (B). End-of-tile wait is
//   vmcnt(8): waits tile kt+1's 8 loads, leaves kt+2's 8 in flight. Never 0.
__global__ __launch_bounds__(512, 2) void gemm1_kernel(const u16* __restrict__ A,
    const u16* __restrict__ Bm, const float* __restrict__ ipb,
    const float* __restrict__ db, u16* __restrict__ proj, u16* __restrict__ gate,
    u16* __restrict__ drive, u16* __restrict__ delta) {
  extern __shared__ u16 lds[];
  const int tid = threadIdx.x;
  int bM, bN; sched_blk(ROWS/256, NCAT/256, 8, 4, bM, bN);

  // ---- staging source addresses (per-thread, pre-swizzled) ----
  const int rS = tid >> 3;                        // lds row 0..63 (j adds 64/128/192)
  const int cS = (tid & 7) ^ (rS & 7);            // swizzled 16B chunk
  const int pB = (rS & 15) * 4 + (rS >> 4);       // B N-permute within 64-quarter
  const u16* gA = A  + (size_t)(bM*256 + rS)*D_MODEL + cS*8;
  const u16* gB = Bm + (size_t)(bN*256 + pB)*D_MODEL + cS*8;
  u16* dA = lds + tid*8;
  u16* dB = lds + 16384 + tid*8;

#define STAGE_A(SLOT, KT) do { const u16* s_ = gA + (KT)*64; u16* d_ = dA + (SLOT); \
    glds16(s_, d_); glds16(s_+64*D_MODEL, d_+4096); \
    glds16(s_+128*D_MODEL, d_+8192); glds16(s_+192*D_MODEL, d_+12288); } while(0)
#define STAGE_B(SLOT, KT) do { const u16* s_ = gB + (KT)*64; u16* d_ = dB + (SLOT); \
    glds16(s_, d_); glds16(s_+64*D_MODEL, d_+4096); \
    glds16(s_+128*D_MODEL, d_+8192); glds16(s_+192*D_MODEL, d_+12288); } while(0)

  // ---- fragment read offsets (u16 units) ----
  const int lane = tid & 63, wid = tid >> 6;
  const int wm = wid >> 2, wn = wid & 3;          // 2M x 4N waves
  const int kx0 = ((lane>>4) ^ (lane&7)) * 8;     // swizzled chunk for kk=0
  const int kx1 = kx0 ^ 32;                       // kk=1 (chunk+4 under XOR)
  const int aW0 = wm*8192 + (lane&15)*64 + kx0;
  const int aW1 = wm*8192 + (lane&15)*64 + kx1;
  const int bWc = 16384 + (wn>>1)*8192 + (wn&1)*4096 + (lane&15)*64;
  const int bW0 = bWc + kx0, bW1 = bWc + kx1;

  f32x4 acc[8][4];
  #pragma unroll
  for (int m=0;m<8;m++)
    #pragma unroll
    for (int n=0;n<4;n++) acc[m][n] = (f32x4){0.f,0.f,0.f,0.f};
  bf16x8 af[4][2], bf[4][2];

  // ---- prologue: stage K-tiles 0 and 1 ----
  STAGE_A(0, 0);     STAGE_B(0, 0);
  STAGE_A(32768, 1); STAGE_B(32768, 1);
  asm volatile("s_waitcnt vmcnt(8)" ::: "memory");   // tile 0 landed; tile 1 in flight
  __builtin_amdgcn_s_barrier();

#define WAIT_PHASE do { \
    asm volatile("s_waitcnt lgkmcnt(0)" ::: "memory"); \
    __builtin_amdgcn_sched_barrier(0); \
    __builtin_amdgcn_s_barrier(); \
    __builtin_amdgcn_s_setprio(1); } while(0)
#define END_PHASE do { \
    __builtin_amdgcn_s_setprio(0); \
    __builtin_amdgcn_s_barrier(); } while(0)

  #pragma unroll 2
  for (int kt = 0; kt < 8; ++kt) {
    const int sb = (kt & 1) << 15;
    // ---------- P0: read A mh=0 + B n0,n1 ----------
    #pragma unroll
    for (int mm=0; mm<4; ++mm) {
      af[mm][0] = *(const bf16x8*)&lds[sb + aW0 + mm*1024];
      af[mm][1] = *(const bf16x8*)&lds[sb + aW1 + mm*1024];
    }
    bf[0][0] = *(const bf16x8*)&lds[sb + bW0];
    bf[0][1] = *(const bf16x8*)&lds[sb + bW1];
    bf[1][0] = *(const bf16x8*)&lds[sb + bW0 + 1024];
    bf[1][1] = *(const bf16x8*)&lds[sb + bW1 + 1024];
    WAIT_PHASE;
    #pragma unroll
    for (int mm=0;mm<4;++mm) {
      acc[mm][0] = MFMA16(af[mm][0], bf[0][0], acc[mm][0]);
      acc[mm][0] = MFMA16(af[mm][1], bf[0][1], acc[mm][0]);
      acc[mm][1] = MFMA16(af[mm][0], bf[1][0], acc[mm][1]);
      acc[mm][1] = MFMA16(af[mm][1], bf[1][1], acc[mm][1]);
    }
    END_PHASE;
    // ---------- P1: read B n2,n3 ----------
    bf[2][0] = *(const bf16x8*)&lds[sb + bW0 + 2048];
    bf[2][1] = *(const bf16x8*)&lds[sb + bW1 + 2048];
    bf[3][0] = *(const bf16x8*)&lds[sb + bW0 + 3072];
    bf[3][1] = *(const bf16x8*)&lds[sb + bW1 + 3072];
    WAIT_PHASE;
    #pragma unroll
    for (int mm=0;mm<4;++mm) {
      acc[mm][2] = MFMA16(af[mm][0], bf[2][0], acc[mm][2]);
      acc[mm][2] = MFMA16(af[mm][1], bf[2][1], acc[mm][2]);
      acc[mm][3] = MFMA16(af[mm][0], bf[3][0], acc[mm][3]);
      acc[mm][3] = MFMA16(af[mm][1], bf[3][1], acc[mm][3]);
    }
    END_PHASE;
    // ---------- P2: read A mh=1; stage A of tile kt+2 into freed slot ----------
    #pragma unroll
    for (int mm=0; mm<4; ++mm) {
      af[mm][0] = *(const bf16x8*)&lds[sb + aW0 + 4096 + mm*1024];
      af[mm][1] = *(const bf16x8*)&lds[sb + aW1 + 4096 + mm*1024];
    }
    WAIT_PHASE;                                    // after this, slot sb fully read
    if (kt < 6) STAGE_A(sb, kt+2);
    #pragma unroll
    for (int mm=0;mm<4;++mm) {
      acc[4+mm][2] = MFMA16(af[mm][0], bf[2][0], acc[4+mm][2]);
      acc[4+mm][2] = MFMA16(af[mm][1], bf[2][1], acc[4+mm][2]);
      acc[4+mm][3] = MFMA16(af[mm][0], bf[3][0], acc[4+mm][3]);
      acc[4+mm][3] = MFMA16(af[mm][1], bf[3][1], acc[4+mm][3]);
    }
    END_PHASE;
    // ---------- P3: no ds_reads; stage B of kt+2; counted end-of-tile wait ----------
    if (kt < 6) STAGE_B(sb, kt+2);
    __builtin_amdgcn_s_setprio(1);
    #pragma unroll
    for (int mm=0;mm<4;++mm) {
      acc[4+mm][0] = MFMA16(af[mm][0], bf[0][0], acc[4+mm][0]);
      acc[4+mm][0] = MFMA16(af[mm][1], bf[0][1], acc[4+mm][0]);
      acc[4+mm][1] = MFMA16(af[mm][0], bf[1][0], acc[4+mm][1]);
      acc[4+mm][1] = MFMA16(af[mm][1], bf[1][1], acc[4+mm][1]);
    }
    __builtin_amdgcn_s_setprio(0);
    if (kt < 6) { asm volatile("s_waitcnt vmcnt(8)" ::: "memory"); }  // kt+1 landed, kt+2 flying
    else        { asm volatile("s_waitcnt vmcnt(0)" ::: "memory"); }
    __builtin_amdgcn_s_barrier();
  }
#undef STAGE_A
#undef STAGE_B

  // ---- epilogue: bias + activation, packed 4-col stores ----
  const int g = bN >> 2;                     // 0 proj, 1 gate, 2 drive, 3 delta
  u16* outp = (g==0)?proj:(g==1)?gate:(g==2)?drive:delta;
  const int colb = bN*256 + wn*64 + (lane&15)*4;
  const float4 b4 = (colb < 3072) ? *(const float4*)&ipb[colb]
                                  : *(const float4*)&db[colb-3072];
  const float* bp = (const float*)&b4;
  const int lcolb = colb & (INNER-1);
  #pragma unroll
  for (int m=0;m<8;m++) {
    const int row0 = bM*256 + wm*128 + m*16 + ((lane>>4)<<2);
    #pragma unroll
    for (int r=0;r<4;r++) {
      float a4[4];
      #pragma unroll
      for (int n=0;n<4;n++) {
        float v = acc[m][n][r] + bp[n];
        if (g==0)      a4[n] = v * sigf(v);
        else if (g==1) a4[n] = sigf(v);
        else if (g==2) a4[n] = 2.f*sigf(2.f*v) - 1.f;
        else           a4[n] = fmaxf(sigf(v), 1e-4f);
      }
      u32 lo = (u32)f2bf(a4[0]) | ((u32)f2bf(a4[1])<<16);
      u32 hi = (u32)f2bf(a4[2]) | ((u32)f2bf(a4[3])<<16);
      *(uint2*)&outp[(size_t)(row0+r)*INNER + lcolb] = make_uint2(lo, hi);
    }
  }
}

// ---------------- GEMM2 mainloop (r3 structure, 128x128, triple-buffered) ----------------
__device__ __forceinline__ void gemm_main(const u16* __restrict__ A,
    const u16* __restrict__ Bm, int K, int nkt, int bM, int bN,
    u16* lA, u16* lB, f32x4 acc[4][4]) {
  const int tid = threadIdx.x;
  const int l6  = tid >> 2;
  const int sg  = (tid & 3) ^ (l6 & 3);
  const int pB  = (l6 & 15) * 4 + ((l6 >> 4) & 3);
  const u16* gA = A  + (size_t)(bM*128 + l6)*K + sg*8;
  const u16* gB = Bm + (size_t)(bN*128 + pB)*K + sg*8;
  u16* dA = lA + tid*8;
  u16* dB = lB + tid*8;
  const size_t rstep = (size_t)64*K;

#define STAGE_T(koff, bufo) do { \
    const u16* sA = gA + (koff); const u16* sB = gB + (koff); \
    glds16(sA,         dA + (bufo));        glds16(sA + rstep, dA + (bufo) + 2048); \
    glds16(sB,         dB + (bufo));        glds16(sB + rstep, dB + (bufo) + 2048); \
  } while (0)

  STAGE_T(0, 0);
  STAGE_T(32, 4096);
  asm volatile("s_waitcnt vmcnt(4)" ::: "memory");
  __builtin_amdgcn_s_barrier();

  const int lane = tid & 63, wv = tid >> 6;
  const int wm = wv >> 1, wn = wv & 1;
  const int kx = ((lane>>4) ^ (lane&3)) * 8;
  const int aoff = (wm*64 + (lane&15))*32 + kx;
  const int boff = (wn*64 + (lane&15))*32 + kx;

  int cur = 0, stg = 8192;
  for (int kt = 0; kt < nkt; ++kt) {
    bf16x8 af[4], bfr[4];
    #pragma unroll
    for (int m=0;m<4;m++) af[m]  = *(const bf16x8*)&lA[cur + aoff + m*512];
    #pragma unroll
    for (int n=0;n<4;n++) bfr[n] = *(const bf16x8*)&lB[cur + boff + n*512];
    asm volatile("s_waitcnt lgkmcnt(0)" ::: "memory");
    __builtin_amdgcn_sched_barrier(0);
    __builtin_amdgcn_s_barrier();
    if (kt + 2 < nkt) STAGE_T((kt+2)*32, stg);
    #pragma unroll
    for (int m=0;m<4;m++)
      #pragma unroll
      for (int n=0;n<4;n++)
        acc[m][n] = MFMA16(af[m], bfr[n], acc[m][n]);
    if (kt + 2 < nkt) { asm volatile("s_waitcnt vmcnt(4)" ::: "memory"); }
    else              { asm volatile("s_waitcnt vmcnt(0)" ::: "memory"); }
    __builtin_amdgcn_s_barrier();
    cur += 4096; if (cur == 12288) cur = 0;
    stg += 4096; if (stg == 12288) stg = 0;
  }
#undef STAGE_T
}

// ---------------- GEMM2: z @ out_proj_w^T + bias + residual (fp32 out) ----------------
__global__ __launch_bounds__(256, 3) void gemm2_kernel(const u16* __restrict__ A,
    const u16* __restrict__ Bm, const float* __restrict__ ob,
    const float* __restrict__ resid, float* __restrict__ out) {
  __shared__ u16 lA[12288], lB[12288];
  f32x4 acc[4][4];
  #pragma unroll
  for (int m=0;m<4;m++)
    #pragma unroll
    for (int n=0;n<4;n++) acc[m][n] = (f32x4){0.f,0.f,0.f,0.f};
  int bM, bN; sched_blk(ROWS/128, D_MODEL/128, 8, 4, bM, bN);
  gemm_main(A, Bm, INNER, INNER/32, bM, bN, lA, lB, acc);
  const int lane = threadIdx.x & 63, wv = threadIdx.x >> 6;
  const int wm = wv>>1, wn = wv&1;
  const int colb = bN*128 + wn*64 + (lane&15)*4;
  const float4 ob4 = *(const float4*)&ob[colb];
  #pragma unroll
  for (int m=0;m<4;m++) {
    const int row0 = bM*128 + wm*64 + m*16 + ((lane>>4)<<2);
    #pragma unroll
    for (int r=0;r<4;r++) {
      const size_t idx = (size_t)(row0+r)*D_MODEL + colb;
      float4 rs = *(const float4*)&resid[idx];
      float4 o;
      o.x = acc[m][0][r] + ob4.x + rs.x;
      o.y = acc[m][1][r] + ob4.y + rs.y;
      o.z = acc[m][2][r] + ob4.z + rs.z;
      o.w = acc[m][3][r] + ob4.w + rs.w;
      *(float4*)&out[idx] = o;
    }
  }
}

// ---------------- scan pass 1: per-chunk local scan (zero init), save chunk-final ----------------
__global__ __launch_bounds__(256) void scan1_kernel(const u16* __restrict__ delta,
    const u16* __restrict__ drive, const float* __restrict__ sm,
    float* __restrict__ cS) {
  const int blk = blockIdx.x;
  const int half = blk & 1, ch = (blk>>1) & (NCHUNK-1), b = blk >> 6;
  const int c0 = half*512 + threadIdx.x*2;
  const float a0 = sigf(sm[c0]), a1 = sigf(sm[c0+1]);
  float s0 = 0.f, s1 = 0.f;
  size_t base = ((size_t)b*SEQ + ch*CHUNK)*INNER + c0;
  for (int t=0;t<CHUNK;t++) {
    u32 dl = *(const u32*)(delta + base);
    u32 dv = *(const u32*)(drive + base);
    s0 = a0*s0 + bf2f(dl & 0xffffu)*bf2f(dv & 0xffffu);
    s1 = a1*s1 + bf2f(dl >> 16)*bf2f(dv >> 16);
    base += INNER;
  }
  const size_t o = ((size_t)b*NCHUNK + ch)*INNER + c0;
  cS[o] = s0; cS[o+1] = s1;
}

// ---------------- scan pass 2: serial combine over 32 chunks -> exclusive carries ----------------
__global__ __launch_bounds__(256) void scan2_kernel(const float* __restrict__ sm,
    const float* __restrict__ cS, float* __restrict__ carry) {
  const int idx = blockIdx.x*256 + threadIdx.x;      // 0..4095
  const int b = idx >> 9, c0 = (idx & 511)*2;
  const float a0 = sigf(sm[c0]), a1 = sigf(sm[c0+1]);
  float A0 = a0, A1 = a1;
  #pragma unroll
  for (int i=0;i<6;i++){ A0*=A0; A1*=A1; }           // a^64 = a^CHUNK
  float cr0 = 0.f, cr1 = 0.f;
  for (int ch=0; ch<NCHUNK; ch++) {
    const size_t o = ((size_t)b*NCHUNK + ch)*INNER + c0;
    carry[o] = cr0; carry[o+1] = cr1;
    cr0 = A0*cr0 + cS[o];
    cr1 = A1*cr1 + cS[o+1];
  }
}

// ---------------- scan pass 3: finish scan + causal conv + gating -> z (bf16) ----------------
__global__ __launch_bounds__(256) void scan3_kernel(const u16* __restrict__ proj,
    const u16* __restrict__ gate, const u16* __restrict__ delta,
    const u16* __restrict__ drive, const float* __restrict__ carry,
    const float* __restrict__ sm, const float* __restrict__ cw,
    const float* __restrict__ cb, const float* __restrict__ sk,
    u16* __restrict__ z) {
  const int blk = blockIdx.x;
  const int half = blk & 1, ch = (blk>>1) & (NCHUNK-1), b = blk >> 6;
  const int c0 = half*512 + threadIdx.x*2;
  const float a0 = sigf(sm[c0]), a1 = sigf(sm[c0+1]);
  const float cb0 = cb[c0], cb1 = cb[c0+1];
  const float sk0 = sk[c0], sk1 = sk[c0+1];
  const float w00=cw[c0*4+0], w01=cw[c0*4+1], w02=cw[c0*4+2], w03=cw[c0*4+3];
  const float w10=cw[c0*4+4], w11=cw[c0*4+5], w12=cw[c0*4+6], w13=cw[c0*4+7];
  const size_t o = ((size_t)b*NCHUNK + ch)*INNER + c0;
  float s0 = carry[o], s1 = carry[o+1];
  const int t0 = ch*CHUNK;
  const size_t rowb = (size_t)b*SEQ*INNER + c0;
  float pa0=0,pb0=0,pc0=0, pa1=0,pb1=0,pc1=0;
  if (ch > 0) {
    u32 u3 = *(const u32*)(proj + rowb + (size_t)(t0-3)*INNER);
    u32 u2 = *(const u32*)(proj + rowb + (size_t)(t0-2)*INNER);
    u32 u1 = *(const u32*)(proj + rowb + (size_t)(t0-1)*INNER);
    pa0 = bf2f(u3&0xffffu); pa1 = bf2f(u3>>16);
    pb0 = bf2f(u2&0xffffu); pb1 = bf2f(u2>>16);
    pc0 = bf2f(u1&0xffffu); pc1 = bf2f(u1>>16);
  }
  size_t base = rowb + (size_t)t0*INNER;
  for (int t=0;t<CHUNK;t++) {
    u32 pu = *(const u32*)(proj + base);
    const float pd0 = bf2f(pu&0xffffu), pd1 = bf2f(pu>>16);
    const float co0 = w00*pa0 + w01*pb0 + w02*pc0 + w03*pd0 + cb0;
    const float co1 = w10*pa1 + w11*pb1 + w12*pc1 + w13*pd1 + cb1;
    pa0=pb0; pb0=pc0; pc0=pd0;  pa1=pb1; pb1=pc1; pc1=pd1;
    u32 dl = *(const u32*)(delta + base);
    u32 dv = *(const u32*)(drive + base);
    s0 = a0*s0 + bf2f(dl&0xffffu)*bf2f(dv&0xffffu);
    s1 = a1*s1 + bf2f(dl>>16)*bf2f(dv>>16);
    u32 gu = *(const u32*)(gate + base);
    const float z0 = (s0 + sk0*co0)*bf2f(gu&0xffffu);
    const float z1 = (s1 + sk1*co1)*bf2f(gu>>16);
    *(u32*)(z + base) = (u32)f2bf(z0) | ((u32)f2bf(z1)<<16);
    base += INNER;
  }
}

extern "C" void kernel_launch(void* const* d_in, const int* in_sizes, int n_in,
                              void* d_out, int out_size, void* d_ws, size_t ws_size,
                              hipStream_t stream) {
  const float* x    = (const float*)d_in[0];
  const float* ln_w = (const float*)d_in[1];
  const float* ln_b = (const float*)d_in[2];
  const float* ipw  = (const float*)d_in[3];
  const float* ipb  = (const float*)d_in[4];
  const float* cw   = (const float*)d_in[5];
  const float* cb   = (const float*)d_in[6];
  const float* dw   = (const float*)d_in[7];
  const float* db   = (const float*)d_in[8];
  const float* sm   = (const float*)d_in[9];
  const float* sk   = (const float*)d_in[10];
  const float* opw  = (const float*)d_in[11];
  const float* opb  = (const float*)d_in[12];
  float* out = (float*)d_out;

  uint8_t* w = (uint8_t*)d_ws;
  u16* xn    = (u16*)w;  w += (size_t)ROWS*D_MODEL*2;
  u16* wcat  = (u16*)w;  w += (size_t)NCAT*D_MODEL*2;
  u16* wout  = (u16*)w;  w += (size_t)D_MODEL*INNER*2;
  u16* proj  = (u16*)w;  w += (size_t)ROWS*INNER*2;
  u16* gate  = (u16*)w;  w += (size_t)ROWS*INNER*2;
  u16* drv   = (u16*)w;  w += (size_t)ROWS*INNER*2;
  u16* dlt   = (u16*)w;  w += (size_t)ROWS*INNER*2;
  u16* z     = (u16*)w;  w += (size_t)ROWS*INNER*2;
  float* cS    = (float*)w; w += (size_t)BATCH*NCHUNK*INNER*4;
  float* carry = (float*)w; w += (size_t)BATCH*NCHUNK*INNER*4;

  ln_kernel<<<ROWS/4, 256, 0, stream>>>(x, ln_w, ln_b, xn);
  cvt_kernel<<<2048, 256, 0, stream>>>(ipw, wcat, 3072*512);
  cvt_kernel<<<1024, 256, 0, stream>>>(dw, wcat + (size_t)3072*512, 1024*512);
  cvt_kernel<<<1024, 256, 0, stream>>>(opw, wout, 512*1024);
  gemm1_kernel<<<(ROWS/256)*(NCAT/256), 512, 131072, stream>>>(xn, wcat, ipb, db, proj, gate, drv, dlt);
  scan1_kernel<<<BATCH*NCHUNK*2, 256, 0, stream>>>(dlt, drv, sm, cS);
  scan2_kernel<<<16, 256, 0, stream>>>(sm, cS, carry);
  scan3_kernel<<<BATCH*NCHUNK*2, 256, 0, stream>>>(proj, gate, dlt, drv, carry, sm, cw, cb, sk, z);
  gemm2_kernel<<<(ROWS/128)*(D_MODEL/128), 256, 0, stream>>>(z, wout, opb, x, out);
}

// Round 6
// 168.073 us; speedup vs baseline: 1.3851x; 1.3851x over previous
//
#include <hip/hip_runtime.h>
#include <stdint.h>

#define D_MODEL 512
#define INNER   1024
#define NCAT    4096
#define BATCH   8
#define SEQ     2048
#define ROWS    (BATCH*SEQ)
#define LN_EPS  1e-5f
#define CHUNK   64
#define NCHUNK  (SEQ/CHUNK)

typedef unsigned short u16;
typedef unsigned int   u32;
typedef __attribute__((ext_vector_type(8))) short bf16x8;
typedef __attribute__((ext_vector_type(4))) float f32x4;

__device__ __forceinline__ u16 f2bf(float f) {
  u32 u = __builtin_bit_cast(u32, f);
  return (u16)((u + 0x7FFFu + ((u >> 16) & 1u)) >> 16);
}
__device__ __forceinline__ float bf2f(u32 lo) {
  return __builtin_bit_cast(float, lo << 16);
}
__device__ __forceinline__ float sigf(float x){ return 1.f/(1.f+__expf(-x)); }

__device__ __forceinline__ void glds16(const void* g, void* l) {
  __builtin_amdgcn_global_load_lds((const __attribute__((address_space(1))) void*)g,
                                   (__attribute__((address_space(3))) void*)l, 16, 0, 0);
}

#define MFMA16(a,b,c) __builtin_amdgcn_mfma_f32_16x16x32_bf16((a),(b),(c),0,0,0)

// ---------------- LayerNorm: one wave per row of 512, write bf16 ----------------
__global__ __launch_bounds__(256) void ln_kernel(const float* __restrict__ x,
    const float* __restrict__ lw, const float* __restrict__ lb,
    u16* __restrict__ xn) {
  const int row  = blockIdx.x * 4 + (threadIdx.x >> 6);
  const int lane = threadIdx.x & 63;
  const float4* xr = (const float4*)(x + (size_t)row * D_MODEL);
  float4 v0 = xr[lane*2], v1 = xr[lane*2+1];
  float s  = v0.x+v0.y+v0.z+v0.w + v1.x+v1.y+v1.z+v1.w;
  float s2 = v0.x*v0.x+v0.y*v0.y+v0.z*v0.z+v0.w*v0.w
           + v1.x*v1.x+v1.y*v1.y+v1.z*v1.z+v1.w*v1.w;
  #pragma unroll
  for (int o=32;o;o>>=1){ s += __shfl_xor(s,o); s2 += __shfl_xor(s2,o); }
  const float mu = s * (1.f/D_MODEL);
  const float rs = rsqrtf(s2*(1.f/D_MODEL) - mu*mu + LN_EPS);
  const float4* wv = (const float4*)lw; const float4* bv = (const float4*)lb;
  float4 w0 = wv[lane*2], w1 = wv[lane*2+1];
  float4 b0 = bv[lane*2], b1 = bv[lane*2+1];
  u32 p0 = (u32)f2bf((v0.x-mu)*rs*w0.x+b0.x) | ((u32)f2bf((v0.y-mu)*rs*w0.y+b0.y)<<16);
  u32 p1 = (u32)f2bf((v0.z-mu)*rs*w0.z+b0.z) | ((u32)f2bf((v0.w-mu)*rs*w0.w+b0.w)<<16);
  u32 p2 = (u32)f2bf((v1.x-mu)*rs*w1.x+b1.x) | ((u32)f2bf((v1.y-mu)*rs*w1.y+b1.y)<<16);
  u32 p3 = (u32)f2bf((v1.z-mu)*rs*w1.z+b1.z) | ((u32)f2bf((v1.w-mu)*rs*w1.w+b1.w)<<16);
  ((uint4*)(xn + (size_t)row * D_MODEL))[lane] = make_uint4(p0,p1,p2,p3);
}

// ---------------- weight convert + reorder + bias concat (single launch) ----------
// wcat rows: [0..2047] = in_proj rows 0..2047 (proj|gate)
//            [2048+2c] = in_proj row 2048+c (drive), [2048+2c+1] = delta_w row c
// bcat matches column layout.
__global__ __launch_bounds__(256) void cvt_all_kernel(const float* __restrict__ ipw,
    const float* __restrict__ dw, const float* __restrict__ opw,
    const float* __restrict__ ipb, const float* __restrict__ db,
    u16* __restrict__ wcat, u16* __restrict__ wout, float* __restrict__ bcat) {
  const int i = blockIdx.x*256 + threadIdx.x;
  const int NW1 = NCAT*D_MODEL, NW2 = D_MODEL*INNER, STR = gridDim.x*256;
  for (int idx = i; idx < NW1; idx += STR) {
    const int r = idx >> 9, c = idx & 511;
    float v;
    if (r < 2048) v = ipw[idx];
    else {
      const int rr = r - 2048;
      v = (rr & 1) ? dw[(size_t)(rr>>1)*D_MODEL + c]
                   : ipw[(size_t)(2048 + (rr>>1))*D_MODEL + c];
    }
    wcat[idx] = f2bf(v);
  }
  for (int idx = i; idx < NW2; idx += STR) wout[idx] = f2bf(opw[idx]);
  if (i < NCAT) {
    float b;
    if (i < 2048) b = ipb[i];
    else { const int rr = i - 2048; b = (rr & 1) ? db[rr>>1] : ipb[2048 + (rr>>1)]; }
    bcat[i] = b;
  }
}

// ---------------- block swizzle: XCD-chunked + L2-sized (GMxGN) groups ----------------
__device__ __forceinline__ void sched_blk(int nbm, int nbn, int GM, int GN,
                                          int& bM, int& bN) {
  const int nwg = nbm * nbn;
  const int bid = blockIdx.x;
  const int cpx = nwg >> 3;
  const int swz = (bid & 7) * cpx + (bid >> 3);   // contiguous chunk per XCD
  const int gsz = GM * GN;
  const int g   = swz / gsz, loc = swz - g * gsz;
  const int ngn = nbn / GN;
  const int gm  = g / ngn,  gn  = g - gm * ngn;
  bM = gm * GM + (loc % GM);
  bN = gn * GN + (loc / GM);
}

// ---------------- MFMA GEMM mainloop: 128x128, BK=32, triple-buffered LDS,
// ONE barrier per K-iter, counted vmcnt(4), compiler-scheduled lgkm waits.
// Safety: a wave's ds_reads of buf[cur] retire before its own MFMAs (compiler
// waitcnt), hence before it reaches the barrier, hence before any wave's
// next-iter STAGE overwrites that buffer. vmcnt(4) before the barrier
// guarantees buf[(kt+1)%3] landed for the next iteration. --------------------
__device__ __forceinline__ void gemm_main(const u16* __restrict__ A,
    const u16* __restrict__ Bm, int K, int nkt, int bM, int bN,
    u16* lA, u16* lB, f32x4 acc[4][4]) {
  const int tid = threadIdx.x;
  const int l6  = tid >> 2;                        // LDS row (first 64-half)
  const int sg  = (tid & 3) ^ (l6 & 3);            // XOR-permuted k-seg
  const int pB  = (l6 & 15) * 4 + ((l6 >> 4) & 3); // B N-row permute
  const u16* gA = A  + (size_t)(bM*128 + l6)*K + sg*8;
  const u16* gB = Bm + (size_t)(bN*128 + pB)*K + sg*8;
  u16* dA = lA + tid*8;
  u16* dB = lB + tid*8;
  const size_t rstep = (size_t)64*K;

#define STAGE_T(koff, bufo) do { \
    const u16* sA = gA + (koff); const u16* sB = gB + (koff); \
    glds16(sA,         dA + (bufo));        glds16(sA + rstep, dA + (bufo) + 2048); \
    glds16(sB,         dB + (bufo));        glds16(sB + rstep, dB + (bufo) + 2048); \
  } while (0)

  STAGE_T(0, 0);
  STAGE_T(32, 4096);
  asm volatile("s_waitcnt vmcnt(4)" ::: "memory");
  __builtin_amdgcn_s_barrier();
  __builtin_amdgcn_sched_barrier(0);

  const int lane = tid & 63, wv = tid >> 6;
  const int wm = wv >> 1, wn = wv & 1;
  const int kx = ((lane>>4) ^ (lane&3)) * 8;
  const int aoff = (wm*64 + (lane&15))*32 + kx;
  const int boff = (wn*64 + (lane&15))*32 + kx;

  int cur = 0, stg = 8192;
  for (int kt = 0; kt < nkt; ++kt) {
    bf16x8 af[4], bfr[4];
    #pragma unroll
    for (int m=0;m<4;m++) af[m]  = *(const bf16x8*)&lA[cur + aoff + m*512];
    #pragma unroll
    for (int n=0;n<4;n++) bfr[n] = *(const bf16x8*)&lB[cur + boff + n*512];
    if (kt + 2 < nkt) STAGE_T((kt+2)*32, stg);
    #pragma unroll
    for (int m=0;m<4;m++)
      #pragma unroll
      for (int n=0;n<4;n++)
        acc[m][n] = MFMA16(af[m], bfr[n], acc[m][n]);
    if (kt + 2 < nkt) { asm volatile("s_waitcnt vmcnt(4)" ::: "memory"); }
    else              { asm volatile("s_waitcnt vmcnt(0)" ::: "memory"); }
    __builtin_amdgcn_s_barrier();
    __builtin_amdgcn_sched_barrier(0);
    cur += 4096; if (cur == 12288) cur = 0;
    stg += 4096; if (stg == 12288) stg = 0;
  }
#undef STAGE_T
}

// ---------------- GEMM1: xn @ wcat^T + bcat, fused activations.
// Regions (128-col blocks): 0-7 proj(silu), 8-15 gate(sigmoid),
// 16-31 paired (even col=drive->tanh, odd col=delta->clamped sigmoid),
// epilogue writes d = drive_act * delta_act (bf16, half the columns). -------
__global__ __launch_bounds__(256, 3) void gemm1_kernel(const u16* __restrict__ A,
    const u16* __restrict__ Bm, const float* __restrict__ bcat,
    u16* __restrict__ proj, u16* __restrict__ gate, u16* __restrict__ dbuf) {
  __shared__ u16 lA[12288], lB[12288];
  f32x4 acc[4][4];
  #pragma unroll
  for (int m=0;m<4;m++)
    #pragma unroll
    for (int n=0;n<4;n++) acc[m][n] = (f32x4){0.f,0.f,0.f,0.f};
  int bM, bN; sched_blk(ROWS/128, NCAT/128, 16, 8, bM, bN);
  gemm_main(A, Bm, D_MODEL, D_MODEL/32, bM, bN, lA, lB, acc);
  const int lane = threadIdx.x & 63, wv = threadIdx.x >> 6;
  const int wm = wv>>1, wn = wv&1;
  const int colb = bN*128 + wn*64 + (lane&15)*4;   // 4 consecutive reordered cols
  const float4 b4 = *(const float4*)&bcat[colb];
  const float* bp = (const float*)&b4;
  if (colb < 2048) {
    u16* outp = (colb < 1024) ? proj : gate;
    const int lcolb = colb & (INNER-1);
    #pragma unroll
    for (int m=0;m<4;m++) {
      const int row0 = bM*128 + wm*64 + m*16 + ((lane>>4)<<2);
      #pragma unroll
      for (int r=0;r<4;r++) {
        float a4[4];
        #pragma unroll
        for (int n=0;n<4;n++) {
          float v = acc[m][n][r] + bp[n];
          a4[n] = (colb < 1024) ? v * sigf(v) : sigf(v);
        }
        u32 lo = (u32)f2bf(a4[0]) | ((u32)f2bf(a4[1])<<16);
        u32 hi = (u32)f2bf(a4[2]) | ((u32)f2bf(a4[3])<<16);
        *(uint2*)&outp[(size_t)(row0+r)*INNER + lcolb] = make_uint2(lo, hi);
      }
    }
  } else {
    const int ch0 = (colb - 2048) >> 1;            // 2 channels per lane
    #pragma unroll
    for (int m=0;m<4;m++) {
      const int row0 = bM*128 + wm*64 + m*16 + ((lane>>4)<<2);
      #pragma unroll
      for (int r=0;r<4;r++) {
        const float v0 = acc[m][0][r] + bp[0];     // drive ch0
        const float v1 = acc[m][1][r] + bp[1];     // delta ch0
        const float v2 = acc[m][2][r] + bp[2];     // drive ch0+1
        const float v3 = acc[m][3][r] + bp[3];     // delta ch0+1
        const float d0 = (2.f*sigf(2.f*v0) - 1.f) * fmaxf(sigf(v1), 1e-4f);
        const float d1 = (2.f*sigf(2.f*v2) - 1.f) * fmaxf(sigf(v3), 1e-4f);
        *(u32*)&dbuf[(size_t)(row0+r)*INNER + ch0] = (u32)f2bf(d0) | ((u32)f2bf(d1)<<16);
      }
    }
  }
}

// ---------------- GEMM2: z @ out_proj_w^T + bias + residual (fp32 out) ----------------
__global__ __launch_bounds__(256, 3) void gemm2_kernel(const u16* __restrict__ A,
    const u16* __restrict__ Bm, const float* __restrict__ ob,
    const float* __restrict__ resid, float* __restrict__ out) {
  __shared__ u16 lA[12288], lB[12288];
  f32x4 acc[4][4];
  #pragma unroll
  for (int m=0;m<4;m++)
    #pragma unroll
    for (int n=0;n<4;n++) acc[m][n] = (f32x4){0.f,0.f,0.f,0.f};
  int bM, bN; sched_blk(ROWS/128, D_MODEL/128, 8, 4, bM, bN);
  gemm_main(A, Bm, INNER, INNER/32, bM, bN, lA, lB, acc);
  const int lane = threadIdx.x & 63, wv = threadIdx.x >> 6;
  const int wm = wv>>1, wn = wv&1;
  const int colb = bN*128 + wn*64 + (lane&15)*4;
  const float4 ob4 = *(const float4*)&ob[colb];
  #pragma unroll
  for (int m=0;m<4;m++) {
    const int row0 = bM*128 + wm*64 + m*16 + ((lane>>4)<<2);
    #pragma unroll
    for (int r=0;r<4;r++) {
      const size_t idx = (size_t)(row0+r)*D_MODEL + colb;
      float4 rs = *(const float4*)&resid[idx];
      float4 o;
      o.x = acc[m][0][r] + ob4.x + rs.x;
      o.y = acc[m][1][r] + ob4.y + rs.y;
      o.z = acc[m][2][r] + ob4.z + rs.z;
      o.w = acc[m][3][r] + ob4.w + rs.w;
      *(float4*)&out[idx] = o;
    }
  }
}

// ---------------- scan pass 1: per-chunk local scan of d, save chunk-final ------------
__global__ __launch_bounds__(256) void scan1_kernel(const u16* __restrict__ d,
    const float* __restrict__ sm, float* __restrict__ cS) {
  const int blk = blockIdx.x;
  const int half = blk & 1, ch = (blk>>1) & (NCHUNK-1), b = blk >> 6;
  const int c0 = half*512 + threadIdx.x*2;
  const float a0 = sigf(sm[c0]), a1 = sigf(sm[c0+1]);
  float s0 = 0.f, s1 = 0.f;
  size_t base = ((size_t)b*SEQ + ch*CHUNK)*INNER + c0;
  for (int t=0;t<CHUNK;t++) {
    u32 du = *(const u32*)(d + base);
    s0 = a0*s0 + bf2f(du & 0xffffu);
    s1 = a1*s1 + bf2f(du >> 16);
    base += INNER;
  }
  const size_t o = ((size_t)b*NCHUNK + ch)*INNER + c0;
  cS[o] = s0; cS[o+1] = s1;
}

// ---------------- scan pass 2: serial combine over 32 chunks -> exclusive carries ------
__global__ __launch_bounds__(256) void scan2_kernel(const float* __restrict__ sm,
    const float* __restrict__ cS, float* __restrict__ carry) {
  const int idx = blockIdx.x*256 + threadIdx.x;      // 0..4095
  const int b = idx >> 9, c0 = (idx & 511)*2;
  const float a0 = sigf(sm[c0]), a1 = sigf(sm[c0+1]);
  float A0 = a0, A1 = a1;
  #pragma unroll
  for (int i=0;i<6;i++){ A0*=A0; A1*=A1; }           // a^64 = a^CHUNK
  float cr0 = 0.f, cr1 = 0.f;
  for (int ch=0; ch<NCHUNK; ch++) {
    const size_t o = ((size_t)b*NCHUNK + ch)*INNER + c0;
    carry[o] = cr0; carry[o+1] = cr1;
    cr0 = A0*cr0 + cS[o];
    cr1 = A1*cr1 + cS[o+1];
  }
}

// ---------------- scan pass 3: finish scan + causal conv + gating -> z (bf16) ----------
__global__ __launch_bounds__(256) void scan3_kernel(const u16* __restrict__ proj,
    const u16* __restrict__ gate, const u16* __restrict__ d,
    const float* __restrict__ carry, const float* __restrict__ sm,
    const float* __restrict__ cw, const float* __restrict__ cb,
    const float* __restrict__ sk, u16* __restrict__ z) {
  const int blk = blockIdx.x;
  const int half = blk & 1, ch = (blk>>1) & (NCHUNK-1), b = blk >> 6;
  const int c0 = half*512 + threadIdx.x*2;
  const float a0 = sigf(sm[c0]), a1 = sigf(sm[c0+1]);
  const float cb0 = cb[c0], cb1 = cb[c0+1];
  const float sk0 = sk[c0], sk1 = sk[c0+1];
  const float w00=cw[c0*4+0], w01=cw[c0*4+1], w02=cw[c0*4+2], w03=cw[c0*4+3];
  const float w10=cw[c0*4+4], w11=cw[c0*4+5], w12=cw[c0*4+6], w13=cw[c0*4+7];
  const size_t o = ((size_t)b*NCHUNK + ch)*INNER + c0;
  float s0 = carry[o], s1 = carry[o+1];
  const int t0 = ch*CHUNK;
  const size_t rowb = (size_t)b*SEQ*INNER + c0;
  float pa0=0,pb0=0,pc0=0, pa1=0,pb1=0,pc1=0;
  if (ch > 0) {
    u32 u3 = *(const u32*)(proj + rowb + (size_t)(t0-3)*INNER);
    u32 u2 = *(const u32*)(proj + rowb + (size_t)(t0-2)*INNER);
    u32 u1 = *(const u32*)(proj + rowb + (size_t)(t0-1)*INNER);
    pa0 = bf2f(u3&0xffffu); pa1 = bf2f(u3>>16);
    pb0 = bf2f(u2&0xffffu); pb1 = bf2f(u2>>16);
    pc0 = bf2f(u1&0xffffu); pc1 = bf2f(u1>>16);
  }
  size_t base = rowb + (size_t)t0*INNER;
  for (int t=0;t<CHUNK;t++) {
    u32 pu = *(const u32*)(proj + base);
    const float pd0 = bf2f(pu&0xffffu), pd1 = bf2f(pu>>16);
    const float co0 = w00*pa0 + w01*pb0 + w02*pc0 + w03*pd0 + cb0;
    const float co1 = w10*pa1 + w11*pb1 + w12*pc1 + w13*pd1 + cb1;
    pa0=pb0; pb0=pc0; pc0=pd0;  pa1=pb1; pb1=pc1; pc1=pd1;
    u32 du = *(const u32*)(d + base);
    s0 = a0*s0 + bf2f(du&0xffffu);
    s1 = a1*s1 + bf2f(du>>16);
    u32 gu = *(const u32*)(gate + base);
    const float z0 = (s0 + sk0*co0)*bf2f(gu&0xffffu);
    const float z1 = (s1 + sk1*co1)*bf2f(gu>>16);
    *(u32*)(z + base) = (u32)f2bf(z0) | ((u32)f2bf(z1)<<16);
    base += INNER;
  }
}

extern "C" void kernel_launch(void* const* d_in, const int* in_sizes, int n_in,
                              void* d_out, int out_size, void* d_ws, size_t ws_size,
                              hipStream_t stream) {
  const float* x    = (const float*)d_in[0];
  const float* ln_w = (const float*)d_in[1];
  const float* ln_b = (const float*)d_in[2];
  const float* ipw  = (const float*)d_in[3];
  const float* ipb  = (const float*)d_in[4];
  const float* cw   = (const float*)d_in[5];
  const float* cb   = (const float*)d_in[6];
  const float* dw   = (const float*)d_in[7];
  const float* db   = (const float*)d_in[8];
  const float* sm   = (const float*)d_in[9];
  const float* sk   = (const float*)d_in[10];
  const float* opw  = (const float*)d_in[11];
  const float* opb  = (const float*)d_in[12];
  float* out = (float*)d_out;

  uint8_t* w = (uint8_t*)d_ws;
  u16* xn    = (u16*)w;  w += (size_t)ROWS*D_MODEL*2;
  u16* wcat  = (u16*)w;  w += (size_t)NCAT*D_MODEL*2;
  u16* wout  = (u16*)w;  w += (size_t)D_MODEL*INNER*2;
  u16* proj  = (u16*)w;  w += (size_t)ROWS*INNER*2;
  u16* gate  = (u16*)w;  w += (size_t)ROWS*INNER*2;
  u16* dbuf  = (u16*)w;  w += (size_t)ROWS*INNER*2;
  u16* z     = (u16*)w;  w += (size_t)ROWS*INNER*2;
  float* cS    = (float*)w; w += (size_t)BATCH*NCHUNK*INNER*4;
  float* carry = (float*)w; w += (size_t)BATCH*NCHUNK*INNER*4;
  float* bcat  = (float*)w; w += (size_t)NCAT*4;

  ln_kernel<<<ROWS/4, 256, 0, stream>>>(x, ln_w, ln_b, xn);
  cvt_all_kernel<<<1024, 256, 0, stream>>>(ipw, dw, opw, ipb, db, wcat, wout, bcat);
  gemm1_kernel<<<(ROWS/128)*(NCAT/128), 256, 0, stream>>>(xn, wcat, bcat, proj, gate, dbuf);
  scan1_kernel<<<BATCH*NCHUNK*2, 256, 0, stream>>>(dbuf, sm, cS);
  scan2_kernel<<<16, 256, 0, stream>>>(sm, cS, carry);
  scan3_kernel<<<BATCH*NCHUNK*2, 256, 0, stream>>>(proj, gate, dbuf, carry, sm, cw, cb, sk, z);
  gemm2_kernel<<<(ROWS/128)*(D_MODEL/128), 256, 0, stream>>>(z, wout, opb, x, out);
}